// Round 12
// baseline (198.830 us; speedup 1.0000x reference)
//
#include <hip/hip_runtime.h>

#define NN 100000
#define NE 600000
#define D  128
#define CHUNK 1024
#define NCH ((NN + CHUNK - 1) / CHUNK)   // 98
#define NT (NN / 16)                     // 6250 node-tiles (exact)

typedef __attribute__((ext_vector_type(8))) short short8;
typedef __attribute__((ext_vector_type(4))) float floatx4;

__device__ __forceinline__ unsigned short f2bf(float f) {
    union { float f; unsigned int u; } a; a.f = f;
    unsigned int r = a.u + 0x7fff + ((a.u >> 16) & 1);   // RNE
    return (unsigned short)(r >> 16);
}
__device__ __forceinline__ float bf2f(unsigned short h) {
    union { unsigned int u; float f; } a; a.u = ((unsigned int)h) << 16;
    return a.f;
}

// ---------------- CSR build ----------------

__global__ void hist_kernel(const int* __restrict__ dst, int* __restrict__ counts, int e) {
    int i = blockIdx.x * blockDim.x + threadIdx.x;
    if (i < e) atomicAdd(&counts[dst[i]], 1);
}

__global__ __launch_bounds__(256) void chunk_sum_kernel(const int* __restrict__ counts,
                                                        int* __restrict__ bsum, int n) {
    __shared__ int s[256];
    int c = blockIdx.x, t = threadIdx.x;
    int sum = 0;
    int end = (c + 1) * CHUNK; if (end > n) end = n;
    for (int i = c * CHUNK + t; i < end; i += 256) sum += counts[i];
    s[t] = sum; __syncthreads();
    for (int off = 128; off > 0; off >>= 1) {
        if (t < off) s[t] += s[t + off];
        __syncthreads();
    }
    if (t == 0) bsum[c] = s[0];
}

__global__ __launch_bounds__(128) void chunk_scan_kernel(const int* __restrict__ bsum,
                                                         int* __restrict__ bpre,
                                                         int* __restrict__ offsets) {
    __shared__ int s[128];
    int t = threadIdx.x;
    int v = (t < NCH) ? bsum[t] : 0;
    s[t] = v; __syncthreads();
    for (int off = 1; off < 128; off <<= 1) {
        int u = (t >= off) ? s[t - off] : 0;
        __syncthreads();
        s[t] += u;
        __syncthreads();
    }
    if (t < NCH) bpre[t] = s[t] - v;
    if (t == 127) offsets[NN] = s[127];
}

__global__ __launch_bounds__(CHUNK) void offsets_kernel(const int* __restrict__ counts,
                                                        const int* __restrict__ bpre,
                                                        int* __restrict__ offsets,
                                                        int* __restrict__ cursor, int n) {
    __shared__ int s[CHUNK];
    int t = threadIdx.x;
    int i = blockIdx.x * CHUNK + t;
    int v = (i < n) ? counts[i] : 0;
    s[t] = v; __syncthreads();
    for (int off = 1; off < CHUNK; off <<= 1) {
        int u = (t >= off) ? s[t - off] : 0;
        __syncthreads();
        s[t] += u;
        __syncthreads();
    }
    if (i < n) {
        int ex = s[t] - v + bpre[blockIdx.x];
        offsets[i] = ex;
        cursor[i]  = ex;
    }
}

__global__ void scatter_kernel(const int* __restrict__ src, const int* __restrict__ dst,
                               int* __restrict__ cursor, int* __restrict__ sorted_src, int e) {
    int i = blockIdx.x * blockDim.x + threadIdx.x;
    if (i < e) {
        int d = dst[i];
        int pos = atomicAdd(&cursor[d], 1);
        sorted_src[pos] = src[i];
    }
}

// ---------------- segment product (writes split-bf16 aggr) ----------------
// 4 edges in flight. Nontemporal: ssrc stream reads + ahi/alo stream writes
// (keep L3 for x, which is re-read ~6x across the gather).

__global__ __launch_bounds__(256) void aggregate_kernel(const float* __restrict__ x,
                                                        const int* __restrict__ offsets,
                                                        const int* __restrict__ ssrc,
                                                        unsigned short* __restrict__ ahi,
                                                        unsigned short* __restrict__ alo,
                                                        int n) {
    int q4 = (threadIdx.x & 31) << 2;   // float4 offset in row
    int slot = threadIdx.x >> 5;        // 0..7
    for (int node = blockIdx.x * 8 + slot; node < n; node += gridDim.x * 8) {
        int b = offsets[node], e2 = offsets[node + 1];
        float4 p0 = make_float4(1.f, 1.f, 1.f, 1.f);
        float4 p1 = make_float4(1.f, 1.f, 1.f, 1.f);
        float4 p2 = make_float4(1.f, 1.f, 1.f, 1.f);
        float4 p3 = make_float4(1.f, 1.f, 1.f, 1.f);
        int i = b;
        for (; i + 4 <= e2; i += 4) {
            int s0 = __builtin_nontemporal_load(&ssrc[i]);
            int s1 = __builtin_nontemporal_load(&ssrc[i + 1]);
            int s2 = __builtin_nontemporal_load(&ssrc[i + 2]);
            int s3 = __builtin_nontemporal_load(&ssrc[i + 3]);
            float4 v0 = *(const float4*)&x[(size_t)s0 * D + q4];
            float4 v1 = *(const float4*)&x[(size_t)s1 * D + q4];
            float4 v2 = *(const float4*)&x[(size_t)s2 * D + q4];
            float4 v3 = *(const float4*)&x[(size_t)s3 * D + q4];
            p0.x *= v0.x; p0.y *= v0.y; p0.z *= v0.z; p0.w *= v0.w;
            p1.x *= v1.x; p1.y *= v1.y; p1.z *= v1.z; p1.w *= v1.w;
            p2.x *= v2.x; p2.y *= v2.y; p2.z *= v2.z; p2.w *= v2.w;
            p3.x *= v3.x; p3.y *= v3.y; p3.z *= v3.z; p3.w *= v3.w;
        }
        for (; i < e2; ++i) {
            int s0 = __builtin_nontemporal_load(&ssrc[i]);
            float4 v0 = *(const float4*)&x[(size_t)s0 * D + q4];
            p0.x *= v0.x; p0.y *= v0.y; p0.z *= v0.z; p0.w *= v0.w;
        }
        float r[4];
        r[0] = (p0.x * p1.x) * (p2.x * p3.x);
        r[1] = (p0.y * p1.y) * (p2.y * p3.y);
        r[2] = (p0.z * p1.z) * (p2.z * p3.z);
        r[3] = (p0.w * p1.w) * (p2.w * p3.w);
        ushort4 h, l;
        h.x = f2bf(r[0]); l.x = f2bf(r[0] - bf2f(h.x));
        h.y = f2bf(r[1]); l.y = f2bf(r[1] - bf2f(h.y));
        h.z = f2bf(r[2]); l.z = f2bf(r[2] - bf2f(h.z));
        h.w = f2bf(r[3]); l.w = f2bf(r[3] - bf2f(h.w));
        unsigned long long hv = *(unsigned long long*)&h;
        unsigned long long lv = *(unsigned long long*)&l;
        __builtin_nontemporal_store(hv, (unsigned long long*)&ahi[(size_t)node * D + q4]);
        __builtin_nontemporal_store(lv, (unsigned long long*)&alo[(size_t)node * D + q4]);
    }
}

// ---------------- W -> split-bf16 MFMA-fragment order ----------------
// wfrag[mat][c][q][lane], 16B per slot. mat: 0=W1hi 1=W1lo 2=W2hi 3=W2lo.
// B-frag for col-tile c, k-chunk q: lane l holds W[c*16 + (l&15)][q*32 + 8*(l>>4) + j].
__global__ void wprep_kernel(const float* __restrict__ W1, const float* __restrict__ W2,
                             short8* __restrict__ wfrag) {
    int idx = blockIdx.x * 256 + threadIdx.x;
    if (idx >= 4096) return;
    int m2 = idx >> 11;                 // 0: W1, 1: W2
    int rem = idx & 2047;
    int c = rem >> 8;
    int q = (rem >> 6) & 3;
    int l = rem & 63;
    const float* W = m2 ? W2 : W1;
    int row = c * 16 + (l & 15);
    int kb = q * 32 + 8 * (l >> 4);
    const float* src = &W[row * D + kb];
    short8 h, lo;
#pragma unroll
    for (int j = 0; j < 8; ++j) {
        float v = src[j];
        unsigned short hh = f2bf(v);
        h[j]  = (short)hh;
        lo[j] = (short)f2bf(v - bf2f(hh));
    }
    wfrag[(((m2 * 2 + 0) * 8 + c) * 4 + q) * 64 + l] = h;
    wfrag[(((m2 * 2 + 1) * 8 + c) * 4 + q) * 64 + l] = lo;
}

// ---------------- fused dual split-bf16 MFMA GEMM + multiply ----------------
// ROUND-12: NO LDS. wfrag is 128 KB, hot in every XCD L2 (and partially L1):
// B-fragments are loaded directly from global per MFMA (64 lanes x 16 B
// consecutive = one coalesced 1 KB wave load, L2-hit). Zero barriers, zero
// staging, waves fully independent -> occupancy limited only by VGPR.
// 256 thr = 4 waves, 1 tile (16 nodes x 128 outputs) per wave.
// Aggr A-fragments issued EARLY (before phase-1 MFMAs) to hide latency.
// Regular out stores (r11's nontemporal stores caused 73 MB write-amp).
// C/D: col=lane&15, row=(lane>>4)*4+reg.
__global__ __launch_bounds__(256)
void fused_kernel(const float* __restrict__ x,
                  const unsigned short* __restrict__ ahi,
                  const unsigned short* __restrict__ alo,
                  const short8* __restrict__ wfrag,
                  const float* __restrict__ b1,
                  const float* __restrict__ b2,
                  float* __restrict__ out) {
    const int lane = threadIdx.x & 63;
    const int wv   = threadIdx.x >> 6;             // 0..3
    const int tile = blockIdx.x * 4 + wv;
    if (tile >= NT) return;

    const int r16 = lane & 15;
    const int g   = lane >> 4;                     // 0..3
    const int base = tile * 16;
    const size_t rowoff = (size_t)(base + r16) * D + g * 8;

    // ---- load + convert x fragments ----
    short8 fh[4], fl[4];
    {
        const float* xr = &x[rowoff];
#pragma unroll
        for (int q = 0; q < 4; ++q) {
            floatx4 v0 = *(const floatx4*)&xr[q * 32];
            floatx4 v1 = *(const floatx4*)&xr[q * 32 + 4];
            short8 h, l;
#pragma unroll
            for (int jj = 0; jj < 4; ++jj) {
                unsigned short hh = f2bf(v0[jj]);
                h[jj] = (short)hh;
                l[jj] = (short)f2bf(v0[jj] - bf2f(hh));
                unsigned short hh2 = f2bf(v1[jj]);
                h[4 + jj] = (short)hh2;
                l[4 + jj] = (short)f2bf(v1[jj] - bf2f(hh2));
            }
            fh[q] = h; fl[q] = l;
        }
    }
    // ---- issue aggr A-operand loads EARLY (consumed in phase 2) ----
    short8 gh[4], gl[4];
    {
        const unsigned short* ahr = &ahi[rowoff];
        const unsigned short* alr = &alo[rowoff];
#pragma unroll
        for (int q = 0; q < 4; ++q) {
            gh[q] = *(const short8*)&ahr[q * 32];
            gl[q] = *(const short8*)&alr[q * 32];
        }
    }

    floatx4 acc[8];
#pragma unroll
    for (int c = 0; c < 8; ++c) acc[c] = (floatx4)0.f;

    // ---- phase 1: h1 = x . W1^T + b1 (W1 fragments from L2) ----
#pragma unroll
    for (int q = 0; q < 4; ++q) {
#pragma unroll
        for (int c = 0; c < 8; ++c) {
            short8 bh = wfrag[((0 * 8 + c) * 4 + q) * 64 + lane];
            short8 bl = wfrag[((1 * 8 + c) * 4 + q) * 64 + lane];
            acc[c] = __builtin_amdgcn_mfma_f32_16x16x32_bf16(fh[q], bh, acc[c], 0, 0, 0);
            acc[c] = __builtin_amdgcn_mfma_f32_16x16x32_bf16(fl[q], bh, acc[c], 0, 0, 0);
            acc[c] = __builtin_amdgcn_mfma_f32_16x16x32_bf16(fh[q], bl, acc[c], 0, 0, 0);
        }
    }
    floatx4 h1[8];
#pragma unroll
    for (int c = 0; c < 8; ++c) {
        float bb = b1[c * 16 + r16];
        floatx4 t = acc[c];
        t[0] += bb; t[1] += bb; t[2] += bb; t[3] += bb;
        h1[c] = t;
        acc[c] = (floatx4)0.f;
    }

    // ---- phase 2: h2 = aggr . W2^T + b2 (W2 fragments from L2) ----
#pragma unroll
    for (int q = 0; q < 4; ++q) {
#pragma unroll
        for (int c = 0; c < 8; ++c) {
            short8 bh = wfrag[((2 * 8 + c) * 4 + q) * 64 + lane];
            short8 bl = wfrag[((3 * 8 + c) * 4 + q) * 64 + lane];
            acc[c] = __builtin_amdgcn_mfma_f32_16x16x32_bf16(gh[q], bh, acc[c], 0, 0, 0);
            acc[c] = __builtin_amdgcn_mfma_f32_16x16x32_bf16(gl[q], bh, acc[c], 0, 0, 0);
            acc[c] = __builtin_amdgcn_mfma_f32_16x16x32_bf16(gh[q], bl, acc[c], 0, 0, 0);
        }
    }
    // ---- epilogue: out = h1 * (acc + b2) ----
#pragma unroll
    for (int c = 0; c < 8; ++c) {
        float bb = b2[c * 16 + r16];
#pragma unroll
        for (int r = 0; r < 4; ++r) {
            out[(size_t)(base + g * 4 + r) * D + c * 16 + r16] =
                h1[c][r] * (acc[c][r] + bb);
        }
    }
}

// ---------------- launch ----------------

extern "C" void kernel_launch(void* const* d_in, const int* in_sizes, int n_in,
                              void* d_out, int out_size, void* d_ws, size_t ws_size,
                              hipStream_t stream) {
    const float* x  = (const float*)d_in[0];
    const int*   ei = (const int*)d_in[1];
    const float* W1 = (const float*)d_in[2];
    const float* b1 = (const float*)d_in[3];
    const float* W2 = (const float*)d_in[4];
    const float* b2 = (const float*)d_in[5];
    float* out = (float*)d_out;

    const int n = NN, e = NE;
    const int* src = ei;          // edge_index[0]
    const int* dst = ei + e;      // edge_index[1]

    char* ws = (char*)d_ws;
    unsigned short* ahi = (unsigned short*)ws;  ws += (size_t)n * D * 2;   // 25.6 MB
    unsigned short* alo = (unsigned short*)ws;  ws += (size_t)n * D * 2;   // 25.6 MB
    short8* wfrag = (short8*)ws;                ws += 8192 * 16;           // 128 KB
    int* counts = (int*)ws;                     ws += (size_t)n * sizeof(int);
    int* offsets = (int*)ws;                    ws += (size_t)(n + 1) * sizeof(int);
    ws += 256 - ((uintptr_t)ws & 255);
    int* cursor = (int*)ws;                     ws += (size_t)n * sizeof(int);
    int* sorted_src = (int*)ws;                 ws += (size_t)e * sizeof(int);
    int* bsum = (int*)ws;                       ws += (size_t)NCH * sizeof(int);
    int* bpre = (int*)ws;                       /* NCH ints */

    hipMemsetAsync(counts, 0, (size_t)n * sizeof(int), stream);
    hist_kernel<<<(e + 255) / 256, 256, 0, stream>>>(dst, counts, e);
    chunk_sum_kernel<<<NCH, 256, 0, stream>>>(counts, bsum, n);
    chunk_scan_kernel<<<1, 128, 0, stream>>>(bsum, bpre, offsets);
    offsets_kernel<<<NCH, CHUNK, 0, stream>>>(counts, bpre, offsets, cursor, n);
    scatter_kernel<<<(e + 255) / 256, 256, 0, stream>>>(src, dst, cursor, sorted_src, e);
    wprep_kernel<<<16, 256, 0, stream>>>(W1, W2, wfrag);
    aggregate_kernel<<<2048, 256, 0, stream>>>(x, offsets, sorted_src, ahi, alo, n);

    fused_kernel<<<(NT + 3) / 4, 256, 0, stream>>>(x, ahi, alo, wfrag, b1, b2, out);
}

// Round 13
// 159.285 us; speedup vs baseline: 1.2483x; 1.2483x over previous
//
#include <hip/hip_runtime.h>

#define NN 100000
#define NE 600000
#define D  128
#define CHUNK 1024
#define NCH ((NN + CHUNK - 1) / CHUNK)   // 98
#define NT (NN / 16)                     // 6250 node-tiles (exact)

typedef __attribute__((ext_vector_type(8))) short short8;
typedef __attribute__((ext_vector_type(4))) float floatx4;

__device__ __forceinline__ unsigned short f2bf(float f) {
    union { float f; unsigned int u; } a; a.f = f;
    unsigned int r = a.u + 0x7fff + ((a.u >> 16) & 1);   // RNE
    return (unsigned short)(r >> 16);
}
__device__ __forceinline__ float bf2f(unsigned short h) {
    union { unsigned int u; float f; } a; a.u = ((unsigned int)h) << 16;
    return a.f;
}

// ---------------- CSR build ----------------

__global__ void hist_kernel(const int* __restrict__ dst, int* __restrict__ counts, int e) {
    int i = blockIdx.x * blockDim.x + threadIdx.x;
    if (i < e) atomicAdd(&counts[dst[i]], 1);
}

__global__ __launch_bounds__(256) void chunk_sum_kernel(const int* __restrict__ counts,
                                                        int* __restrict__ bsum, int n) {
    __shared__ int s[256];
    int c = blockIdx.x, t = threadIdx.x;
    int sum = 0;
    int end = (c + 1) * CHUNK; if (end > n) end = n;
    for (int i = c * CHUNK + t; i < end; i += 256) sum += counts[i];
    s[t] = sum; __syncthreads();
    for (int off = 128; off > 0; off >>= 1) {
        if (t < off) s[t] += s[t + off];
        __syncthreads();
    }
    if (t == 0) bsum[c] = s[0];
}

__global__ __launch_bounds__(128) void chunk_scan_kernel(const int* __restrict__ bsum,
                                                         int* __restrict__ bpre,
                                                         int* __restrict__ offsets) {
    __shared__ int s[128];
    int t = threadIdx.x;
    int v = (t < NCH) ? bsum[t] : 0;
    s[t] = v; __syncthreads();
    for (int off = 1; off < 128; off <<= 1) {
        int u = (t >= off) ? s[t - off] : 0;
        __syncthreads();
        s[t] += u;
        __syncthreads();
    }
    if (t < NCH) bpre[t] = s[t] - v;
    if (t == 127) offsets[NN] = s[127];
}

__global__ __launch_bounds__(CHUNK) void offsets_kernel(const int* __restrict__ counts,
                                                        const int* __restrict__ bpre,
                                                        int* __restrict__ offsets,
                                                        int* __restrict__ cursor, int n) {
    __shared__ int s[CHUNK];
    int t = threadIdx.x;
    int i = blockIdx.x * CHUNK + t;
    int v = (i < n) ? counts[i] : 0;
    s[t] = v; __syncthreads();
    for (int off = 1; off < CHUNK; off <<= 1) {
        int u = (t >= off) ? s[t - off] : 0;
        __syncthreads();
        s[t] += u;
        __syncthreads();
    }
    if (i < n) {
        int ex = s[t] - v + bpre[blockIdx.x];
        offsets[i] = ex;
        cursor[i]  = ex;
    }
}

__global__ void scatter_kernel(const int* __restrict__ src, const int* __restrict__ dst,
                               int* __restrict__ cursor, int* __restrict__ sorted_src, int e) {
    int i = blockIdx.x * blockDim.x + threadIdx.x;
    if (i < e) {
        int d = dst[i];
        int pos = atomicAdd(&cursor[d], 1);
        sorted_src[pos] = src[i];
    }
}

// ---------------- W -> split-bf16 MFMA-fragment order ----------------
// wfrag[mat][c][q][lane], 16B per slot. mat: 0=W1hi 1=W1lo 2=W2hi 3=W2lo.
// B-frag for col-tile c, k-chunk q: lane l holds W[c*16 + (l&15)][q*32 + 8*(l>>4) + j].
__global__ void wprep_kernel(const float* __restrict__ W1, const float* __restrict__ W2,
                             short8* __restrict__ wfrag) {
    int idx = blockIdx.x * 256 + threadIdx.x;
    if (idx >= 4096) return;
    int m2 = idx >> 11;                 // 0: W1, 1: W2
    int rem = idx & 2047;
    int c = rem >> 8;
    int q = (rem >> 6) & 3;
    int l = rem & 63;
    const float* W = m2 ? W2 : W1;
    int row = c * 16 + (l & 15);
    int kb = q * 32 + 8 * (l >> 4);
    const float* src = &W[row * D + kb];
    short8 h, lo;
#pragma unroll
    for (int j = 0; j < 8; ++j) {
        float v = src[j];
        unsigned short hh = f2bf(v);
        h[j]  = (short)hh;
        lo[j] = (short)f2bf(v - bf2f(hh));
    }
    wfrag[(((m2 * 2 + 0) * 8 + c) * 4 + q) * 64 + l] = h;
    wfrag[(((m2 * 2 + 1) * 8 + c) * 4 + q) * 64 + l] = lo;
}

// ---------------- FULLY fused: gather-product + dual split-bf16 GEMM ----------------
// ROUND-13: segment product folded INTO the GEMM kernel — no ahi/alo round trip
// (saves 51 MB write + 51 MB read + one kernel). r10's proven core: 512 thr,
// 64 KB LDS, sequential W staging (stage W1 -> phase1 -> restage W2 -> phase2).
// Gather: lane (r16,g) multiplies dims q*32+g*8+[0,8) of node base+r16 over its
// CSR segment; 4-lane groups read 128 B/edge contiguous, x2-unrolled. Product
// converted to split-bf16 in-register (gh/gl) = phase-2 A operand.
// C/D: col=lane&15, row=(lane>>4)*4+reg. Regular out stores (r11: NT = write-amp).
__global__ __launch_bounds__(512, 1)
void fused_kernel(const float* __restrict__ x,
                  const int* __restrict__ offsets,
                  const int* __restrict__ ssrc,
                  const short8* __restrict__ wfrag,
                  const float* __restrict__ b1,
                  const float* __restrict__ b2,
                  float* __restrict__ out) {
    __shared__ short8 sW[2 * 8 * 4 * 64];          // 64 KB: one matrix (hi+lo)

    const int lane = threadIdx.x & 63;
    const int wv   = threadIdx.x >> 6;             // 0..7
    const int r16  = lane & 15;
    const int g    = lane >> 4;                    // 0..3

    const int tile = blockIdx.x * 8 + wv;
    const bool live = (tile < NT);
    const int base = tile * 16;
    const size_t rowoff = live ? ((size_t)(base + r16) * D + g * 8) : 0;

    // ---- stage W1 (hi+lo), 64 KB ----
    for (int i = threadIdx.x; i < 4096; i += 512) sW[i] = wfrag[i];

    // ---- gather: prod over incoming edges of node base+r16, this lane's 32 dims ----
    floatx4 p[8];
#pragma unroll
    for (int k = 0; k < 8; ++k) p[k] = (floatx4)1.f;
    if (live) {
        const int node = base + r16;
        int eb = offsets[node], ee = offsets[node + 1];
        int i = eb;
        for (; i + 2 <= ee; i += 2) {
            int s0 = ssrc[i], s1 = ssrc[i + 1];
            const float* xr0 = &x[(size_t)s0 * D + g * 8];
            const float* xr1 = &x[(size_t)s1 * D + g * 8];
#pragma unroll
            for (int q = 0; q < 4; ++q) {
                floatx4 a0 = *(const floatx4*)&xr0[q * 32];
                floatx4 a1 = *(const floatx4*)&xr0[q * 32 + 4];
                floatx4 c0 = *(const floatx4*)&xr1[q * 32];
                floatx4 c1 = *(const floatx4*)&xr1[q * 32 + 4];
                p[2 * q]     *= a0 * c0;
                p[2 * q + 1] *= a1 * c1;
            }
        }
        if (i < ee) {
            int s0 = ssrc[i];
            const float* xr0 = &x[(size_t)s0 * D + g * 8];
#pragma unroll
            for (int q = 0; q < 4; ++q) {
                p[2 * q]     *= *(const floatx4*)&xr0[q * 32];
                p[2 * q + 1] *= *(const floatx4*)&xr0[q * 32 + 4];
            }
        }
    }
    // ---- convert product to split bf16 (phase-2 A operand) ----
    short8 gh[4], gl[4];
#pragma unroll
    for (int q = 0; q < 4; ++q) {
        short8 h, l;
#pragma unroll
        for (int jj = 0; jj < 4; ++jj) {
            unsigned short hh = f2bf(p[2 * q][jj]);
            h[jj] = (short)hh;
            l[jj] = (short)f2bf(p[2 * q][jj] - bf2f(hh));
            unsigned short hh2 = f2bf(p[2 * q + 1][jj]);
            h[4 + jj] = (short)hh2;
            l[4 + jj] = (short)f2bf(p[2 * q + 1][jj] - bf2f(hh2));
        }
        gh[q] = h; gl[q] = l;
    }

    __syncthreads();                               // W1 staged

    floatx4 acc[8];
#pragma unroll
    for (int c = 0; c < 8; ++c) acc[c] = (floatx4)0.f;

    floatx4 h1[8];
    if (live) {
        // ---- phase 1: h1 = x . W1^T + b1 (x converted per-q, low live set) ----
        const float* xr = &x[rowoff];
#pragma unroll
        for (int q = 0; q < 4; ++q) {
            floatx4 v0 = *(const floatx4*)&xr[q * 32];
            floatx4 v1 = *(const floatx4*)&xr[q * 32 + 4];
            short8 fh, fl;
#pragma unroll
            for (int jj = 0; jj < 4; ++jj) {
                unsigned short hh = f2bf(v0[jj]);
                fh[jj] = (short)hh;
                fl[jj] = (short)f2bf(v0[jj] - bf2f(hh));
                unsigned short hh2 = f2bf(v1[jj]);
                fh[4 + jj] = (short)hh2;
                fl[4 + jj] = (short)f2bf(v1[jj] - bf2f(hh2));
            }
#pragma unroll
            for (int c = 0; c < 8; ++c) {
                short8 bh = sW[((0 * 8 + c) * 4 + q) * 64 + lane];
                short8 bl = sW[((1 * 8 + c) * 4 + q) * 64 + lane];
                acc[c] = __builtin_amdgcn_mfma_f32_16x16x32_bf16(fh, bh, acc[c], 0, 0, 0);
                acc[c] = __builtin_amdgcn_mfma_f32_16x16x32_bf16(fl, bh, acc[c], 0, 0, 0);
                acc[c] = __builtin_amdgcn_mfma_f32_16x16x32_bf16(fh, bl, acc[c], 0, 0, 0);
            }
        }
#pragma unroll
        for (int c = 0; c < 8; ++c) {
            float bb = b1[c * 16 + r16];
            floatx4 t = acc[c];
            t[0] += bb; t[1] += bb; t[2] += bb; t[3] += bb;
            h1[c] = t;
            acc[c] = (floatx4)0.f;
        }
    }

    // ---- restage: W2 (hi+lo) into the same LDS ----
    __syncthreads();                                  // everyone done reading W1
    for (int i = threadIdx.x; i < 4096; i += 512) sW[i] = wfrag[4096 + i];
    __syncthreads();

    if (live) {
        // ---- phase 2: h2 = aggr . W2^T + b2 (gh/gl from in-kernel gather) ----
#pragma unroll
        for (int q = 0; q < 4; ++q) {
#pragma unroll
            for (int c = 0; c < 8; ++c) {
                short8 bh = sW[((0 * 8 + c) * 4 + q) * 64 + lane];
                short8 bl = sW[((1 * 8 + c) * 4 + q) * 64 + lane];
                acc[c] = __builtin_amdgcn_mfma_f32_16x16x32_bf16(gh[q], bh, acc[c], 0, 0, 0);
                acc[c] = __builtin_amdgcn_mfma_f32_16x16x32_bf16(gl[q], bh, acc[c], 0, 0, 0);
                acc[c] = __builtin_amdgcn_mfma_f32_16x16x32_bf16(gh[q], bl, acc[c], 0, 0, 0);
            }
        }
        // ---- epilogue: out = h1 * (acc + b2) ----
#pragma unroll
        for (int c = 0; c < 8; ++c) {
            float bb = b2[c * 16 + r16];
#pragma unroll
            for (int r = 0; r < 4; ++r) {
                out[(size_t)(base + g * 4 + r) * D + c * 16 + r16] =
                    h1[c][r] * (acc[c][r] + bb);
            }
        }
    }
}

// ---------------- launch ----------------

extern "C" void kernel_launch(void* const* d_in, const int* in_sizes, int n_in,
                              void* d_out, int out_size, void* d_ws, size_t ws_size,
                              hipStream_t stream) {
    const float* x  = (const float*)d_in[0];
    const int*   ei = (const int*)d_in[1];
    const float* W1 = (const float*)d_in[2];
    const float* b1 = (const float*)d_in[3];
    const float* W2 = (const float*)d_in[4];
    const float* b2 = (const float*)d_in[5];
    float* out = (float*)d_out;

    const int n = NN, e = NE;
    const int* src = ei;          // edge_index[0]
    const int* dst = ei + e;      // edge_index[1]

    char* ws = (char*)d_ws;
    short8* wfrag = (short8*)ws;                ws += 8192 * 16;           // 128 KB
    int* counts = (int*)ws;                     ws += (size_t)n * sizeof(int);
    int* offsets = (int*)ws;                    ws += (size_t)(n + 1) * sizeof(int);
    ws += 256 - ((uintptr_t)ws & 255);
    int* cursor = (int*)ws;                     ws += (size_t)n * sizeof(int);
    int* sorted_src = (int*)ws;                 ws += (size_t)e * sizeof(int);
    int* bsum = (int*)ws;                       ws += (size_t)NCH * sizeof(int);
    int* bpre = (int*)ws;                       /* NCH ints */

    hipMemsetAsync(counts, 0, (size_t)n * sizeof(int), stream);
    hist_kernel<<<(e + 255) / 256, 256, 0, stream>>>(dst, counts, e);
    chunk_sum_kernel<<<NCH, 256, 0, stream>>>(counts, bsum, n);
    chunk_scan_kernel<<<1, 128, 0, stream>>>(bsum, bpre, offsets);
    offsets_kernel<<<NCH, CHUNK, 0, stream>>>(counts, bpre, offsets, cursor, n);
    scatter_kernel<<<(e + 255) / 256, 256, 0, stream>>>(src, dst, cursor, sorted_src, e);
    wprep_kernel<<<16, 256, 0, stream>>>(W1, W2, wfrag);

    fused_kernel<<<(NT + 7) / 8, 512, 0, stream>>>(x, offsets, sorted_src, wfrag, b1, b2, out);
}